// Round 14
// baseline (1436.326 us; speedup 1.0000x reference)
//
#include <hip/hip_runtime.h>
#include <hip/hip_bf16.h>

// ---------------------------------------------------------------------------
// SMN forward. B=512 U=10 L=50 E=200 H=200 V=50000
// ---------------------------------------------------------------------------

typedef __attribute__((ext_vector_type(8))) short short8v;   // 8 bf16 (4 VGPR)
typedef __attribute__((ext_vector_type(4))) float f32x4;

__device__ __forceinline__ float sigm(float x) { return 1.0f / (1.0f + __expf(-x)); }
__device__ __forceinline__ float tanhfast(float x) {
    float e = __expf(2.0f * x);
    return 1.0f - 2.0f / (e + 1.0f);
}
__device__ __forceinline__ float bl(unsigned x) { return __uint_as_float(x << 16); }
__device__ __forceinline__ float bh(unsigned x) { return __uint_as_float(x & 0xffff0000u); }
__device__ __forceinline__ unsigned packbf(float a, float b) {
    union { __hip_bfloat16 h[2]; unsigned u; } cv;
    cv.h[0] = __float2bfloat16(a); cv.h[1] = __float2bfloat16(b);
    return cv.u;
}

// ---------------------------------------------------------------------------
// MFMA GEMM (K=200 specialized): C16[M,N] = bf16(A[M,200] @ W[N,200]^T + bias)
// ---------------------------------------------------------------------------
__global__ __launch_bounds__(256)
void gemm_mfma(const void* __restrict__ Asrc, int a_bf16,
               const int* __restrict__ gidx,
               const float* __restrict__ W, const float* __restrict__ bias,
               __hip_bfloat16* __restrict__ C, int M, int N)
{
    __shared__ __hip_bfloat16 Al[64 * 232];
    __shared__ __hip_bfloat16 Bl[64 * 232];
    const int tid = threadIdx.x;
    const int m0 = blockIdx.x * 64, n0 = blockIdx.y * 64;

    for (int idx = tid; idx < 64 * 29; idx += 256) {
        int r = idx / 29, q = idx - r * 29;
        int k0 = q * 8, row = m0 + r;
        uint4 val = make_uint4(0, 0, 0, 0);
        if (k0 < 200 && row < M) {
            size_t ar = (size_t)(gidx ? gidx[row] : row) * 200 + k0;
            if (a_bf16) {
                val = *(const uint4*)((const __hip_bfloat16*)Asrc + ar);
            } else {
                const float* ap = (const float*)Asrc + ar;
                float4 f0 = *(const float4*)ap;
                float4 f1 = *(const float4*)(ap + 4);
                val.x = packbf(f0.x, f0.y); val.y = packbf(f0.z, f0.w);
                val.z = packbf(f1.x, f1.y); val.w = packbf(f1.z, f1.w);
            }
        }
        *(uint4*)(Al + r * 232 + k0) = val;
    }
    for (int idx = tid; idx < 64 * 29; idx += 256) {
        int r = idx / 29, q = idx - r * 29;
        int k0 = q * 8, row = n0 + r;
        uint4 val = make_uint4(0, 0, 0, 0);
        if (k0 < 200 && row < N) {
            const float* wp = W + (size_t)row * 200 + k0;
            float4 f0 = *(const float4*)wp;
            float4 f1 = *(const float4*)(wp + 4);
            val.x = packbf(f0.x, f0.y); val.y = packbf(f0.z, f0.w);
            val.z = packbf(f1.x, f1.y); val.w = packbf(f1.z, f1.w);
        }
        *(uint4*)(Bl + r * 232 + k0) = val;
    }
    __syncthreads();

    const int wid = tid >> 6, lane = tid & 63;
    const int wm = (wid >> 1) * 32, wn = (wid & 1) * 32;
    const int lrow = lane & 15, lk8 = (lane >> 4) * 8;
    f32x4 acc00 = {0.f, 0.f, 0.f, 0.f}, acc01 = {0.f, 0.f, 0.f, 0.f};
    f32x4 acc10 = {0.f, 0.f, 0.f, 0.f}, acc11 = {0.f, 0.f, 0.f, 0.f};
#pragma unroll
    for (int kk = 0; kk < 7; ++kk) {
        const int kb = kk * 32 + lk8;
        short8v a0 = *(const short8v*)(Al + (wm + lrow) * 232 + kb);
        short8v a1 = *(const short8v*)(Al + (wm + 16 + lrow) * 232 + kb);
        short8v b0 = *(const short8v*)(Bl + (wn + lrow) * 232 + kb);
        short8v b1 = *(const short8v*)(Bl + (wn + 16 + lrow) * 232 + kb);
        acc00 = __builtin_amdgcn_mfma_f32_16x16x32_bf16(a0, b0, acc00, 0, 0, 0);
        acc01 = __builtin_amdgcn_mfma_f32_16x16x32_bf16(a0, b1, acc01, 0, 0, 0);
        acc10 = __builtin_amdgcn_mfma_f32_16x16x32_bf16(a1, b0, acc10, 0, 0, 0);
        acc11 = __builtin_amdgcn_mfma_f32_16x16x32_bf16(a1, b1, acc11, 0, 0, 0);
    }
    const int drow = (lane >> 4) * 4, dcol = lane & 15;
#pragma unroll
    for (int fm = 0; fm < 2; ++fm) {
#pragma unroll
        for (int fn = 0; fn < 2; ++fn) {
            const f32x4 av = (fm == 0) ? (fn == 0 ? acc00 : acc01)
                                       : (fn == 0 ? acc10 : acc11);
            const int gcol = n0 + wn + fn * 16 + dcol;
            if (gcol >= N) continue;
            const float bs = bias ? bias[gcol] : 0.0f;
#pragma unroll
            for (int r = 0; r < 4; ++r) {
                const int grow = m0 + wm + fm * 16 + drow + r;
                if (grow >= M) continue;
                C[(size_t)grow * N + gcol] = __float2bfloat16(av[r] + bs);
            }
        }
    }
}

// ---------------------------------------------------------------------------
// General-K MFMA GEMM: C[M,N] = act(A[M,K] @ W[N,K]^T + bias)
// ---------------------------------------------------------------------------
__global__ __launch_bounds__(256)
void gemm_mfma_k(const void* __restrict__ Asrc, int a_bf16,
                 const float* __restrict__ W, const float* __restrict__ bias,
                 void* __restrict__ Cv, int c_bf16,
                 int M, int N, int K, int act)
{
    __shared__ __align__(16) __hip_bfloat16 As[64 * 136];
    __shared__ __align__(16) __hip_bfloat16 Bs[64 * 136];
    const int tid = threadIdx.x;
    const int m0 = blockIdx.x * 64, n0 = blockIdx.y * 64;
    const int wid = tid >> 6, lane = tid & 63;
    const int wm = (wid >> 1) * 32, wn = (wid & 1) * 32;
    const int lrow = lane & 15, lk8 = (lane >> 4) * 8;
    const bool aAlign16 = a_bf16 && ((K & 7) == 0);

    f32x4 acc00 = {0.f, 0.f, 0.f, 0.f}, acc01 = {0.f, 0.f, 0.f, 0.f};
    f32x4 acc10 = {0.f, 0.f, 0.f, 0.f}, acc11 = {0.f, 0.f, 0.f, 0.f};

    for (int kb = 0; kb < K; kb += 128) {
        for (int idx = tid; idx < 1024; idx += 256) {
            int r = idx >> 4, q = idx & 15;
            int k0 = kb + q * 8, row = m0 + r;
            uint4 av = make_uint4(0, 0, 0, 0);
            if (row < M && k0 < K) {
                size_t base = (size_t)row * K + k0;
                if (a_bf16) {
                    const __hip_bfloat16* ap = (const __hip_bfloat16*)Asrc + base;
                    if (aAlign16 && k0 + 8 <= K) {
                        av = *(const uint4*)ap;
                    } else {
                        unsigned t4[4] = {0, 0, 0, 0};
                        int nv = (K - k0 < 8) ? (K - k0) : 8;
                        for (int e = 0; e < nv; ++e)
                            ((__hip_bfloat16*)t4)[e] = ap[e];
                        av.x = t4[0]; av.y = t4[1]; av.z = t4[2]; av.w = t4[3];
                    }
                } else {
                    const float* ap = (const float*)Asrc + base;
                    float tv[8] = {0, 0, 0, 0, 0, 0, 0, 0};
                    int nv = (K - k0 < 8) ? (K - k0) : 8;
                    for (int e = 0; e < nv; ++e) tv[e] = ap[e];
                    av.x = packbf(tv[0], tv[1]); av.y = packbf(tv[2], tv[3]);
                    av.z = packbf(tv[4], tv[5]); av.w = packbf(tv[6], tv[7]);
                }
            }
            *(uint4*)(As + r * 136 + q * 8) = av;
        }
        for (int idx = tid; idx < 1024; idx += 256) {
            int r = idx >> 4, q = idx & 15;
            int k0 = kb + q * 8, row = n0 + r;
            uint4 bv = make_uint4(0, 0, 0, 0);
            if (row < N && k0 < K) {
                const float* wp = W + (size_t)row * K + k0;
                float tv[8] = {0, 0, 0, 0, 0, 0, 0, 0};
                int nv = (K - k0 < 8) ? (K - k0) : 8;
                for (int e = 0; e < nv; ++e) tv[e] = wp[e];
                bv.x = packbf(tv[0], tv[1]); bv.y = packbf(tv[2], tv[3]);
                bv.z = packbf(tv[4], tv[5]); bv.w = packbf(tv[6], tv[7]);
            }
            *(uint4*)(Bs + r * 136 + q * 8) = bv;
        }
        __syncthreads();
#pragma unroll
        for (int kk = 0; kk < 4; ++kk) {
            const int ko = kk * 32 + lk8;
            short8v a0 = *(const short8v*)(As + (wm + lrow) * 136 + ko);
            short8v a1 = *(const short8v*)(As + (wm + 16 + lrow) * 136 + ko);
            short8v b0 = *(const short8v*)(Bs + (wn + lrow) * 136 + ko);
            short8v b1 = *(const short8v*)(Bs + (wn + 16 + lrow) * 136 + ko);
            acc00 = __builtin_amdgcn_mfma_f32_16x16x32_bf16(a0, b0, acc00, 0, 0, 0);
            acc01 = __builtin_amdgcn_mfma_f32_16x16x32_bf16(a0, b1, acc01, 0, 0, 0);
            acc10 = __builtin_amdgcn_mfma_f32_16x16x32_bf16(a1, b0, acc10, 0, 0, 0);
            acc11 = __builtin_amdgcn_mfma_f32_16x16x32_bf16(a1, b1, acc11, 0, 0, 0);
        }
        __syncthreads();
    }

    const int drow = (lane >> 4) * 4, dcol = lane & 15;
#pragma unroll
    for (int fm = 0; fm < 2; ++fm) {
#pragma unroll
        for (int fn = 0; fn < 2; ++fn) {
            const f32x4 av = (fm == 0) ? (fn == 0 ? acc00 : acc01)
                                       : (fn == 0 ? acc10 : acc11);
            const int gcol = n0 + wn + fn * 16 + dcol;
            if (gcol >= N) continue;
            const float bs = bias ? bias[gcol] : 0.0f;
#pragma unroll
            for (int r = 0; r < 4; ++r) {
                const int grow = m0 + wm + fm * 16 + drow + r;
                if (grow >= M) continue;
                float t = av[r] + bs;
                if (act == 1) t = tanhfast(t);
                if (c_bf16) ((__hip_bfloat16*)Cv)[(size_t)grow * N + gcol] = __float2bfloat16(t);
                else        ((float*)Cv)[(size_t)grow * N + gcol] = t;
            }
        }
    }
}

// ---------------------------------------------------------------------------
// WT_f[200][600] = W_hh_f[600][200]^T  (final GRU only)
// ---------------------------------------------------------------------------
__global__ __launch_bounds__(256)
void transpose_wf(const float* __restrict__ Wf, float* __restrict__ Tf)
{
    int id = blockIdx.x * 256 + threadIdx.x;
    if (id < 120000) {
        int e = id / 600, j = id - e * 600;
        Tf[id] = Wf[(size_t)j * 200 + e];
    }
}

// ---------------------------------------------------------------------------
// Pack Whh [600][200] f32 -> gate-tiled [3][256][224] bf16 (row j = g*256+cc)
// ---------------------------------------------------------------------------
__global__ __launch_bounds__(256)
void pack_whh(const float* __restrict__ Wu, const float* __restrict__ Wr,
              __hip_bfloat16* __restrict__ Du, __hip_bfloat16* __restrict__ Dr)
{
    int idx = blockIdx.x * 256 + threadIdx.x;     // 768*224 = 172032
    if (idx >= 172032) return;
    int j = idx / 224, e = idx - j * 224;
    int g = j >> 8, cc = j & 255;
    bool v = (cc < 200) && (e < 200);
    Du[idx] = __float2bfloat16(v ? Wu[(size_t)(g * 200 + cc) * 200 + e] : 0.0f);
    Dr[idx] = __float2bfloat16(v ? Wr[(size_t)(g * 200 + cc) * 200 + e] : 0.0f);
}

// ---------------------------------------------------------------------------
__global__ __launch_bounds__(256)
void gather_re16(const int* __restrict__ resp, const float* __restrict__ emb,
                 __hip_bfloat16* __restrict__ re16)
{
    int idx = blockIdx.x * 256 + threadIdx.x;
    if (idx < 2560000) {
        int row = idx / 100, q = idx - row * 100;
        float2 v = *(const float2*)(emb + (size_t)resp[row] * 200 + 2 * q);
        ((unsigned*)re16)[idx] = packbf(v.x, v.y);
    }
}

// ---------------------------------------------------------------------------
// MFMA persistent GRU scan v5: register-gate design.
// 176 blocks x 512 thr, 32 rows. W packed [3][256][224]: wave w owns
// col-tiles {2w,2w+1} ACROSS ALL 3 GATES -> r/z/n accs live in the same lane,
// gate math fully in registers: no gh LDS, hf lane-resident, ONE barrier/step
// (double-buffered h16, 29.7 KB total LDS). Archive = deferred LDS->global
// copy under next step's MFMA phase. Arithmetic chain identical to v2.
// ---------------------------------------------------------------------------
__global__ __launch_bounds__(512, 2)
void scan_gru_mfma(const int* __restrict__ utt,
                   const __hip_bfloat16* __restrict__ EPu,
                   const __hip_bfloat16* __restrict__ xpr16,
                   const __hip_bfloat16* __restrict__ Wu16,
                   const __hip_bfloat16* __restrict__ Wr16,
                   const float* __restrict__ bhu, const float* __restrict__ bhr,
                   __hip_bfloat16* __restrict__ ug16,
                   __hip_bfloat16* __restrict__ rg16)
{
    __shared__ __align__(16) __hip_bfloat16 h16[2][32][232];   // 29696 B total

    const int tid = threadIdx.x;
    const bool isResp = (int)blockIdx.x >= 160;
    const int row0 = isResp ? ((int)blockIdx.x - 160) * 32 : (int)blockIdx.x * 32;
    const __hip_bfloat16* Wt = isResp ? Wr16 : Wu16;
    const float* bgate = isResp ? bhr : bhu;
    __hip_bfloat16* arch = isResp ? rg16 : ug16;

    for (int i = tid; i < 2 * 32 * 232 / 8; i += 512)
        ((uint4*)h16)[i] = make_uint4(0, 0, 0, 0);
    __syncthreads();

    const int wid = tid >> 6, lane = tid & 63;
    const int lrow = lane & 15, lk8 = (lane >> 4) * 8;
    const int drow = (lane >> 4) * 4, dcol = lane & 15;
    const int ct0 = 2 * wid, ct1 = 2 * wid + 1;
    const bool u0 = (ct0 <= 12), u1 = (ct1 <= 12);   // tiles with any real cols
    const int c0 = ct0 * 16 + dcol, c1 = ct1 * 16 + dcol;
    const bool g0 = (c0 < 200), g1 = (c1 < 200);     // lane's cols gate-active

    // gate biases hoisted (invariant over t)
    float bgA[3] = {0.f, 0.f, 0.f}, bgB[3] = {0.f, 0.f, 0.f};
    if (g0) { bgA[0] = bgate[c0]; bgA[1] = bgate[200 + c0]; bgA[2] = bgate[400 + c0]; }
    if (g1) { bgB[0] = bgate[c1]; bgB[1] = bgate[200 + c1]; bgB[2] = bgate[400 + c1]; }

    float hfA[2][4] = {{0.f,0.f,0.f,0.f},{0.f,0.f,0.f,0.f}};   // [rb][r] tile0
    float hfB[2][4] = {{0.f,0.f,0.f,0.f},{0.f,0.f,0.f,0.f}};   // tile1

    for (int t = 0; t < 50; ++t) {
        const int buf = t & 1, nxt = buf ^ 1;

        // ---- deferred archive: h16[buf] holds h_{t-1}; store to arch[t-1] ----
        if (t > 0) {
            for (int idx = tid; idx < 800; idx += 512) {
                int rr = idx / 25, q = (idx - rr * 25) * 8;
                uint4 v = *(const uint4*)(&h16[buf][rr][q]);
                *(uint4*)(arch + ((size_t)(row0 + rr) * 50 + (t - 1)) * 200 + q) = v;
            }
        }

        // ---- prefetch xp for this step (hidden under MFMA) ----
        float xvA[2][4][3], xvB[2][4][3];
#pragma unroll
        for (int rb = 0; rb < 2; ++rb)
#pragma unroll
            for (int r = 0; r < 4; ++r) {
                const int grow = row0 + rb * 16 + drow + r;
                const __hip_bfloat16* xp = isResp
                    ? (xpr16 + ((size_t)grow * 50 + t) * 600)
                    : (EPu + (size_t)utt[grow * 50 + t] * 600);
                if (g0) {
                    xvA[rb][r][0] = __bfloat162float(xp[c0]);
                    xvA[rb][r][1] = __bfloat162float(xp[200 + c0]);
                    xvA[rb][r][2] = __bfloat162float(xp[400 + c0]);
                }
                if (g1) {
                    xvB[rb][r][0] = __bfloat162float(xp[c1]);
                    xvB[rb][r][1] = __bfloat162float(xp[200 + c1]);
                    xvB[rb][r][2] = __bfloat162float(xp[400 + c1]);
                }
            }

        // ---- MFMA: acc[tile][rb][gate], B streamed from L2 ----
        f32x4 aA[2][3], aB[2][3];
#pragma unroll
        for (int rb = 0; rb < 2; ++rb)
#pragma unroll
            for (int g = 0; g < 3; ++g) {
                aA[rb][g] = (f32x4){0.f, 0.f, 0.f, 0.f};
                aB[rb][g] = (f32x4){0.f, 0.f, 0.f, 0.f};
            }
#pragma unroll
        for (int kk = 0; kk < 7; ++kk) {
            short8v A0 = *(const short8v*)(&h16[buf][lrow][kk * 32 + lk8]);
            short8v A1 = *(const short8v*)(&h16[buf][16 + lrow][kk * 32 + lk8]);
            if (u0) {
#pragma unroll
                for (int g = 0; g < 3; ++g) {
                    short8v B = *(const short8v*)(Wt +
                        (size_t)(g * 256 + ct0 * 16 + lrow) * 224 + kk * 32 + lk8);
                    aA[0][g] = __builtin_amdgcn_mfma_f32_16x16x32_bf16(A0, B, aA[0][g], 0, 0, 0);
                    aA[1][g] = __builtin_amdgcn_mfma_f32_16x16x32_bf16(A1, B, aA[1][g], 0, 0, 0);
                }
            }
            if (u1) {
#pragma unroll
                for (int g = 0; g < 3; ++g) {
                    short8v B = *(const short8v*)(Wt +
                        (size_t)(g * 256 + ct1 * 16 + lrow) * 224 + kk * 32 + lk8);
                    aB[0][g] = __builtin_amdgcn_mfma_f32_16x16x32_bf16(A0, B, aB[0][g], 0, 0, 0);
                    aB[1][g] = __builtin_amdgcn_mfma_f32_16x16x32_bf16(A1, B, aB[1][g], 0, 0, 0);
                }
            }
        }

        // ---- gate in registers, write h16[nxt] ----
        if (g0) {
#pragma unroll
            for (int rb = 0; rb < 2; ++rb)
#pragma unroll
                for (int r = 0; r < 4; ++r) {
                    const float rr_ = sigm(xvA[rb][r][0] + aA[rb][0][r] + bgA[0]);
                    const float zz  = sigm(xvA[rb][r][1] + aA[rb][1][r] + bgA[1]);
                    const float nn  = tanhfast(xvA[rb][r][2] + rr_ * (aA[rb][2][r] + bgA[2]));
                    const float hn  = (1.0f - zz) * nn + zz * hfA[rb][r];
                    hfA[rb][r] = hn;
                    h16[nxt][rb * 16 + drow + r][c0] = __float2bfloat16(hn);
                }
        }
        if (g1) {
#pragma unroll
            for (int rb = 0; rb < 2; ++rb)
#pragma unroll
                for (int r = 0; r < 4; ++r) {
                    const float rr_ = sigm(xvB[rb][r][0] + aB[rb][0][r] + bgB[0]);
                    const float zz  = sigm(xvB[rb][r][1] + aB[rb][1][r] + bgB[1]);
                    const float nn  = tanhfast(xvB[rb][r][2] + rr_ * (aB[rb][2][r] + bgB[2]));
                    const float hn  = (1.0f - zz) * nn + zz * hfB[rb][r];
                    hfB[rb][r] = hn;
                    h16[nxt][rb * 16 + drow + r][c1] = __float2bfloat16(hn);
                }
        }
        __syncthreads();
    }
    // final archive: h_49 lives in h16[0] (written by step 49)
    for (int idx = tid; idx < 800; idx += 512) {
        int rr = idx / 25, q = (idx - rr * 25) * 8;
        uint4 v = *(const uint4*)(&h16[0][rr][q]);
        *(uint4*)(arch + ((size_t)(row0 + rr) * 50 + 49) * 200 + q) = v;
    }
}

// ---------------------------------------------------------------------------
// Fused m1/m2 match (MFMA) + conv3x3(2->8)+relu+maxpool3x3 per (b,u).
// ---------------------------------------------------------------------------
__global__ __launch_bounds__(256)
void match_conv_pool(const int* __restrict__ utt, const float* __restrict__ emb,
                     const __hip_bfloat16* __restrict__ ug16,
                     const __hip_bfloat16* __restrict__ re16,
                     const __hip_bfloat16* __restrict__ rgA16,
                     const float* __restrict__ cw, const float* __restrict__ cb,
                     __hip_bfloat16* __restrict__ pooled16)
{
    const int bu = blockIdx.x, b = bu / 10;
    __shared__ __align__(16) __hip_bfloat16 As[64 * 232];
    __shared__ __align__(16) __hip_bfloat16 Bs[64 * 232];
    __shared__ float m[2][50][50];
    __shared__ float w[144];
    __shared__ float bsh[8];
    const int tid = threadIdx.x;
    if (tid < 144) w[tid] = cw[tid];
    if (tid >= 144 && tid < 152) bsh[tid - 144] = cb[tid - 144];

    for (int idx = tid; idx < 64 * 29; idx += 256) {
        int r = idx / 29, q = idx - r * 29;
        uint4 av = make_uint4(0, 0, 0, 0), bv = make_uint4(0, 0, 0, 0);
        if (r < 50 && q < 25) {
            const float* ap = emb + (size_t)utt[bu * 50 + r] * 200 + q * 8;
            float4 f0 = *(const float4*)ap;
            float4 f1 = *(const float4*)(ap + 4);
            av.x = packbf(f0.x, f0.y); av.y = packbf(f0.z, f0.w);
            av.z = packbf(f1.x, f1.y); av.w = packbf(f1.z, f1.w);
            bv = *(const uint4*)(re16 + (size_t)b * 10000 + (size_t)r * 200 + q * 8);
        }
        *(uint4*)(As + r * 232 + q * 8) = av;
        *(uint4*)(Bs + r * 232 + q * 8) = bv;
    }
    __syncthreads();

    const int wid = tid >> 6, lane = tid & 63;
    const int wm = (wid >> 1) * 32, wn = (wid & 1) * 32;
    const int lrow = lane & 15, lk8 = (lane >> 4) * 8;
    const int drow = (lane >> 4) * 4, dcol = lane & 15;

#pragma unroll 1
    for (int ch = 0; ch < 2; ++ch) {
        f32x4 acc00 = {0.f, 0.f, 0.f, 0.f}, acc01 = {0.f, 0.f, 0.f, 0.f};
        f32x4 acc10 = {0.f, 0.f, 0.f, 0.f}, acc11 = {0.f, 0.f, 0.f, 0.f};
#pragma unroll
        for (int kk = 0; kk < 7; ++kk) {
            const int kb = kk * 32 + lk8;
            short8v a0 = *(const short8v*)(As + (wm + lrow) * 232 + kb);
            short8v a1 = *(const short8v*)(As + (wm + 16 + lrow) * 232 + kb);
            short8v b0 = *(const short8v*)(Bs + (wn + lrow) * 232 + kb);
            short8v b1 = *(const short8v*)(Bs + (wn + 16 + lrow) * 232 + kb);
            acc00 = __builtin_amdgcn_mfma_f32_16x16x32_bf16(a0, b0, acc00, 0, 0, 0);
            acc01 = __builtin_amdgcn_mfma_f32_16x16x32_bf16(a0, b1, acc01, 0, 0, 0);
            acc10 = __builtin_amdgcn_mfma_f32_16x16x32_bf16(a1, b0, acc10, 0, 0, 0);
            acc11 = __builtin_amdgcn_mfma_f32_16x16x32_bf16(a1, b1, acc11, 0, 0, 0);
        }
#pragma unroll
        for (int fm = 0; fm < 2; ++fm) {
#pragma unroll
            for (int fn = 0; fn < 2; ++fn) {
                const f32x4 av = (fm == 0) ? (fn == 0 ? acc00 : acc01)
                                           : (fn == 0 ? acc10 : acc11);
                const int gcol = wn + fn * 16 + dcol;
                if (gcol >= 50) continue;
#pragma unroll
                for (int r = 0; r < 4; ++r) {
                    const int grow = wm + fm * 16 + drow + r;
                    if (grow < 50) m[ch][grow][gcol] = av[r];
                }
            }
        }
        __syncthreads();
        if (ch == 0) {
            for (int idx = tid; idx < 50 * 25; idx += 256) {
                int r = idx / 25, q = idx - r * 25;
                *(uint4*)(As + r * 232 + q * 8) =
                    *(const uint4*)(ug16 + (size_t)bu * 10000 + (size_t)r * 200 + q * 8);
                *(uint4*)(Bs + r * 232 + q * 8) =
                    *(const uint4*)(rgA16 + (size_t)b * 10000 + (size_t)r * 200 + q * 8);
            }
            __syncthreads();
        }
    }

#pragma unroll
    for (int k = 0; k < 8; ++k) {
        const int o = tid + k * 256;
        const int c = o >> 8, ph = (o >> 4) & 15, pw = o & 15;
        float mx = -1e30f;
#pragma unroll
        for (int p = 0; p < 3; ++p)
#pragma unroll
            for (int q = 0; q < 3; ++q) {
                const int y = ph * 3 + p, x = pw * 3 + q;
                float s = bsh[c];
#pragma unroll
                for (int ci = 0; ci < 2; ++ci)
#pragma unroll
                    for (int dy = 0; dy < 3; ++dy)
#pragma unroll
                        for (int dx = 0; dx < 3; ++dx)
                            s = fmaf(w[(c * 2 + ci) * 9 + dy * 3 + dx],
                                     m[ci][y + dy][x + dx], s);
                s = fmaxf(s, 0.0f);
                mx = fmaxf(mx, s);
            }
        pooled16[(size_t)bu * 2048 + o] = __float2bfloat16(mx);
    }
}

// ---------------------------------------------------------------------------
__global__ __launch_bounds__(256)
void final_gru(const float* __restrict__ xpf, const float* __restrict__ WTf,
               const float* __restrict__ bhf, const float* __restrict__ fw,
               const float* __restrict__ fb, float* __restrict__ out)
{
    const int blk = blockIdx.x;
    const int tid = threadIdx.x;
    __shared__ float h[2][201];
    for (int i = tid; i < 402; i += 256) ((float*)h)[i] = 0.0f;
    __syncthreads();
    const int rr = tid / 100;
    const int j0 = 2 * (tid % 100);
    for (int t = 0; t < 10; ++t) {
        float cR[2] = {}, cZ[2] = {}, cN[2] = {};
        if (tid < 200) {
#pragma unroll 2
            for (int e = 0; e < 200; ++e) {
                const float* w = WTf + (size_t)e * 600;
                float2 wr = *(const float2*)(w + j0);
                float2 wz = *(const float2*)(w + 200 + j0);
                float2 wn = *(const float2*)(w + 400 + j0);
                float hv = h[rr][e];
                cR[0] = fmaf(hv, wr.x, cR[0]); cR[1] = fmaf(hv, wr.y, cR[1]);
                cZ[0] = fmaf(hv, wz.x, cZ[0]); cZ[1] = fmaf(hv, wz.y, cZ[1]);
                cN[0] = fmaf(hv, wn.x, cN[0]); cN[1] = fmaf(hv, wn.y, cN[1]);
            }
        }
        __syncthreads();
        if (tid < 200) {
            const float* xp = xpf + ((size_t)(blk * 2 + rr) * 10 + t) * 600;
#pragma unroll
            for (int j = 0; j < 2; ++j) {
                const int c = j0 + j;
                float rrg = sigm(xp[c] + cR[j] + bhf[c]);
                float zz = sigm(xp[200 + c] + cZ[j] + bhf[200 + c]);
                float nn = tanhfast(xp[400 + c] + rrg * (cN[j] + bhf[400 + c]));
                h[rr][c] = (1.0f - zz) * nn + zz * h[rr][c];
            }
        }
        __syncthreads();
    }
    if (tid < 2) {
        float s = fb[0];
        for (int k = 0; k < 200; ++k) s = fmaf(h[tid][k], fw[k], s);
        out[blk * 2 + tid] = sigm(s);
    }
}

__global__ __launch_bounds__(256)
void fill_out(float* __restrict__ out)
{
    int i = blockIdx.x * 256 + threadIdx.x;
    if (i < 512) out[i] = 0.0f;
}

// ---------------------------------------------------------------------------
extern "C" void kernel_launch(void* const* d_in, const int* in_sizes, int n_in,
                              void* d_out, int out_size, void* d_ws, size_t ws_size,
                              hipStream_t stream)
{
    const int*   utt    = (const int*)d_in[0];
    const int*   resp   = (const int*)d_in[1];
    const float* emb    = (const float*)d_in[2];
    const float* W_ih_u = (const float*)d_in[3];
    const float* W_hh_u = (const float*)d_in[4];
    const float* b_ih_u = (const float*)d_in[5];
    const float* b_hh_u = (const float*)d_in[6];
    const float* W_ih_r = (const float*)d_in[7];
    const float* W_hh_r = (const float*)d_in[8];
    const float* b_ih_r = (const float*)d_in[9];
    const float* b_hh_r = (const float*)d_in[10];
    const float* conv_w = (const float*)d_in[11];
    const float* conv_b = (const float*)d_in[12];
    const float* lin_w  = (const float*)d_in[13];
    const float* lin_b  = (const float*)d_in[14];
    const float* Amat   = (const float*)d_in[15];
    const float* W_ih_f = (const float*)d_in[16];
    const float* W_hh_f = (const float*)d_in[17];
    const float* b_ih_f = (const float*)d_in[18];
    const float* b_hh_f = (const float*)d_in[19];
    const float* flin_w = (const float*)d_in[20];
    const float* flin_b = (const float*)d_in[21];
    float* out = (float*)d_out;
    float* ws  = (float*)d_ws;

    size_t off = 0;
    auto alloc = [&](size_t n) { float* p = ws + off; off += (n + 63) & ~((size_t)63); return p; };
    float* WT_f   = alloc(120000);
    float* Wu16f  = alloc(86016);      // [768,224] bf16
    float* Wr16f  = alloc(86016);      // [768,224] bf16
    float* re16f  = alloc(2560000);    // [25600,200] bf16
    float* EPuf   = alloc(15000000);   // [50000,600] bf16; post-scan: pooled16
    float* xprf   = alloc(7680000);    // [25600,600] bf16; post-scan: mv16/xpf
    float* ug16f  = alloc(25600000);   // [5120,50,200] bf16
    float* rg16f  = alloc(2560000);    // [512,50,200] bf16
    float* rgA16f = alloc(2560000);    // [25600,200] bf16
    // total ~56.3M floats = 225 MB

    if (off * sizeof(float) > ws_size) {
        hipLaunchKernelGGL(fill_out, dim3(2), dim3(256), 0, stream, out);
        return;
    }

    __hip_bfloat16* Wu16  = (__hip_bfloat16*)Wu16f;
    __hip_bfloat16* Wr16  = (__hip_bfloat16*)Wr16f;
    __hip_bfloat16* re16  = (__hip_bfloat16*)re16f;
    __hip_bfloat16* EPu   = (__hip_bfloat16*)EPuf;
    __hip_bfloat16* xpr16 = (__hip_bfloat16*)xprf;
    __hip_bfloat16* ug16  = (__hip_bfloat16*)ug16f;
    __hip_bfloat16* rg16  = (__hip_bfloat16*)rg16f;
    __hip_bfloat16* rgA16 = (__hip_bfloat16*)rgA16f;
    __hip_bfloat16* pooled16 = (__hip_bfloat16*)EPuf;   // [5120,2048] bf16 (EPu dead)
    __hip_bfloat16* mv16     = (__hip_bfloat16*)xprf;   // [5120,50] bf16 (xpr dead)
    float* xpf = xprf + 400000;                          // [5120,600] f32

    // 1. transpose W_hh_f + pack scan weights gate-tiled bf16 [768,224]
    hipLaunchKernelGGL(transpose_wf, dim3(469), dim3(256), 0, stream, W_hh_f, WT_f);
    hipLaunchKernelGGL(pack_whh, dim3(672), dim3(256), 0, stream,
                       W_hh_u, W_hh_r, Wu16, Wr16);
    // 2. response embedding gather (bf16)
    hipLaunchKernelGGL(gather_re16, dim3(10000), dim3(256), 0, stream, resp, emb, re16);
    // 3. EPu = bf16(emb @ W_ih_u^T + b_ih_u)  [MFMA]
    hipLaunchKernelGGL(gemm_mfma, dim3(782, 10), dim3(256), 0, stream,
                       (const void*)emb, 0, (const int*)nullptr, W_ih_u, b_ih_u,
                       EPu, 50000, 600);
    // 4. xpr16 = bf16(emb[resp] @ W_ih_r^T + b_ih_r)  [MFMA]
    hipLaunchKernelGGL(gemm_mfma, dim3(400, 10), dim3(256), 0, stream,
                       (const void*)emb, 0, resp, W_ih_r, b_ih_r,
                       xpr16, 25600, 600);
    // 5. persistent MFMA dual-GRU scan v5 (register-gate, 1 barrier/step)
    hipLaunchKernelGGL(scan_gru_mfma, dim3(176), dim3(512), 0, stream,
                       utt, EPu, xpr16, Wu16, Wr16, b_hh_u, b_hh_r, ug16, rg16);
    // 6. rgA16 = bf16(rg @ Amat^T)  [MFMA]
    hipLaunchKernelGGL(gemm_mfma, dim3(400, 4), dim3(256), 0, stream,
                       (const void*)rg16, 1, (const int*)nullptr, Amat,
                       (const float*)nullptr, rgA16, 25600, 200);
    // 7. fused match (MFMA) + conv + pool (bf16 pooled)
    hipLaunchKernelGGL(match_conv_pool, dim3(5120), dim3(256), 0, stream,
                       utt, emb, ug16, re16, rgA16, conv_w, conv_b, pooled16);
    // 8. mv16 = tanh(pooled16 @ lin_w^T + lin_b)  [MFMA, K=2048]
    hipLaunchKernelGGL(gemm_mfma_k, dim3(80, 1), dim3(256), 0, stream,
                       (const void*)pooled16, 1, lin_w, lin_b,
                       (void*)mv16, 1, 5120, 50, 2048, 1);
    // 9. xpf = mv16 @ W_ih_f^T + b_ih_f  [MFMA, K=50]
    hipLaunchKernelGGL(gemm_mfma_k, dim3(80, 10), dim3(256), 0, stream,
                       (const void*)mv16, 1, W_ih_f, b_ih_f,
                       (void*)xpf, 0, 5120, 600, 50, 0);
    // 10. final GRU + logit + sigmoid
    hipLaunchKernelGGL(final_gru, dim3(256), dim3(256), 0, stream,
                       xpf, WT_f, b_hh_f, flin_w, flin_b, out);
}